// Round 19
// baseline (1475.744 us; speedup 1.0000x reference)
//
#include <hip/hip_runtime.h>
#include <cstdint>
#include <cstddef>

typedef __attribute__((ext_vector_type(4))) float f32x4;
typedef __attribute__((ext_vector_type(8))) short short8;
typedef __attribute__((ext_vector_type(4))) unsigned int u32x4;

static const int TS = 2048;      // sequence length
static const int DM = 2048;      // d_model
static const int NHEAD = 16, NKVH = 8, HDIM = 128;
static const int FFD = 8192;
static const int NVOC = 32000;
static const int QKVN = 4096;    // fused QKV output width (2048 q + 1024 k + 1024 v)

__device__ __forceinline__ unsigned short f2bf(float f){
  unsigned int u = __builtin_bit_cast(unsigned int, f);
  u += 0x7FFFu + ((u >> 16) & 1u);
  return (unsigned short)(u >> 16);
}
__device__ __forceinline__ float bf2f(short h){
  unsigned int u = ((unsigned int)(unsigned short)h) << 16;
  return __builtin_bit_cast(float, u);
}
__device__ __forceinline__ f32x4 mfma16(short8 a, short8 b, f32x4 c){
  return __builtin_amdgcn_mfma_f32_16x16x32_bf16(a, b, c, 0, 0, 0);
}
__device__ __forceinline__ void gload16(const void* g, void* l){
  __builtin_amdgcn_global_load_lds(
      (const __attribute__((address_space(1))) unsigned int*)g,
      (__attribute__((address_space(3))) unsigned int*)l, 16, 0, 0);
}
// tiled operand layout: [rowtile r>>4][ktile k>>5] 512-elem fragment-major
// subtile; within: elem (r&15, k&31) at ((k&31)>>3)*128 + (r&15)*8 + (k&7).
__device__ __forceinline__ long toff(int r, int k, int ldk){
  return ((long)((r >> 4) * ldk + (k >> 5)) << 9)
       + (((k & 31) >> 3) << 7) + ((r & 15) << 3) + (k & 7);
}

// ---------------- RoPE tables ----------------
__global__ void rope_tables_k(float* __restrict__ cosT, float* __restrict__ sinT){
  int idx = blockIdx.x * 256 + threadIdx.x;   // TS*64 entries
  int s = idx >> 6, j = idx & 63;
  float inv = exp2f(-(float)j * (13.287712379549449f / 64.0f)); // 10000^(-j/64)
  float ang = (float)s * inv;
  cosT[idx] = cosf(ang);
  sinT[idx] = sinf(ang);
}

// ---------------- embedding gather ----------------
__global__ void embed_k(const int* __restrict__ ids, const float* __restrict__ E,
                        float* __restrict__ h){
  int s = blockIdx.x, tid = threadIdx.x;
  long id = ids[s];
  const f32x4* src = (const f32x4*)(E + id * (long)DM);
  f32x4* dst = (f32x4*)(h + (long)s * DM);
  dst[tid] = src[tid];
  dst[tid + 256] = src[tid + 256];
}

// ---------------- RMSNorm (f32 in -> bf16 out, TILED) ----------------
__global__ void rmsnorm_k(const float* __restrict__ x, const float* __restrict__ w,
                          short* __restrict__ out){
  int s = blockIdx.x, tid = threadIdx.x;
  const float* row = x + (long)s * DM;
  f32x4 v0 = *(const f32x4*)&row[tid * 8];
  f32x4 v1 = *(const f32x4*)&row[tid * 8 + 4];
  float ss = v0[0]*v0[0] + v0[1]*v0[1] + v0[2]*v0[2] + v0[3]*v0[3]
           + v1[0]*v1[0] + v1[1]*v1[1] + v1[2]*v1[2] + v1[3]*v1[3];
  #pragma unroll
  for (int off = 32; off; off >>= 1) ss += __shfl_xor(ss, off);
  __shared__ float sred[4];
  int wave = tid >> 6, lane = tid & 63;
  if (lane == 0) sred[wave] = ss;
  __syncthreads();
  float tot = sred[0] + sred[1] + sred[2] + sred[3];
  float r = rsqrtf(tot * (1.0f / (float)DM) + 1e-5f);
  f32x4 w0 = *(const f32x4*)&w[tid * 8];
  f32x4 w1 = *(const f32x4*)&w[tid * 8 + 4];
  short8 o;
  #pragma unroll
  for (int j = 0; j < 4; j++) o[j] = (short)f2bf(v0[j] * r * w0[j]);
  #pragma unroll
  for (int j = 0; j < 4; j++) o[4 + j] = (short)f2bf(v1[j] * r * w1[j]);
  *(short8*)&out[toff(s, tid * 8, DM >> 5)] = o;
}

// ---------------- fused split-K reduce + RMSNorm ----------------
__global__ void reduce_rms_k(const float* __restrict__ p, float* __restrict__ h,
                             const float* __restrict__ w, short* __restrict__ out){
  const long stride = (long)TS * DM;
  int s = blockIdx.x, tid = threadIdx.x;
  long i = (long)s * DM + tid * 8;
  f32x4 a0 = *(const f32x4*)&h[i];
  f32x4 a1 = *(const f32x4*)&h[i + 4];
  {
    f32x4 v0 = *(const f32x4*)&p[i];
    f32x4 v1 = *(const f32x4*)&p[i + stride];
    f32x4 v2 = *(const f32x4*)&p[i + 2 * stride];
    f32x4 v3 = *(const f32x4*)&p[i + 3 * stride];
    a0 = a0 + ((v0 + v1) + (v2 + v3));
  }
  {
    f32x4 v0 = *(const f32x4*)&p[i + 4];
    f32x4 v1 = *(const f32x4*)&p[i + 4 + stride];
    f32x4 v2 = *(const f32x4*)&p[i + 4 + 2 * stride];
    f32x4 v3 = *(const f32x4*)&p[i + 4 + 3 * stride];
    a1 = a1 + ((v0 + v1) + (v2 + v3));
  }
  *(f32x4*)&h[i] = a0;
  *(f32x4*)&h[i + 4] = a1;
  float ss = a0[0]*a0[0] + a0[1]*a0[1] + a0[2]*a0[2] + a0[3]*a0[3]
           + a1[0]*a1[0] + a1[1]*a1[1] + a1[2]*a1[2] + a1[3]*a1[3];
  #pragma unroll
  for (int off = 32; off; off >>= 1) ss += __shfl_xor(ss, off);
  __shared__ float sred[4];
  int wave = tid >> 6, lane = tid & 63;
  if (lane == 0) sred[wave] = ss;
  __syncthreads();
  float tot = sred[0] + sred[1] + sred[2] + sred[3];
  float r = rsqrtf(tot * (1.0f / (float)DM) + 1e-5f);
  f32x4 w0 = *(const f32x4*)&w[tid * 8];
  f32x4 w1 = *(const f32x4*)&w[tid * 8 + 4];
  short8 o;
  #pragma unroll
  for (int j = 0; j < 4; j++) o[j] = (short)f2bf(a0[j] * r * w0[j]);
  #pragma unroll
  for (int j = 0; j < 4; j++) o[4 + j] = (short)f2bf(a1[j] * r * w1[j]);
  *(short8*)&out[toff(s, tid * 8, DM >> 5)] = o;
}

// ---------------- weight transpose+convert: B[K][N] f32 -> tiled Bt (bf16) ----------------
__global__ void transpose_k(const float* __restrict__ B, short* __restrict__ Bt,
                            int K, int N){
  __shared__ float t[64][65];
  int tid = threadIdx.x;
  int kb = blockIdx.y * 64, nb = blockIdx.x * 64;
  int r0 = tid >> 4, c4 = tid & 15;
  const int ldk = K >> 5;
  #pragma unroll
  for (int p = 0; p < 4; p++){
    int r = r0 + p * 16;
    f32x4 v = *(const f32x4*)&B[(long)(kb + r) * N + nb + c4 * 4];
    t[r][c4*4+0] = v[0]; t[r][c4*4+1] = v[1]; t[r][c4*4+2] = v[2]; t[r][c4*4+3] = v[3];
  }
  __syncthreads();
  int wave = tid >> 6, lane = tid & 63;
  #pragma unroll
  for (int p = 0; p < 2; p++){
    int s = wave * 2 + p;
    int rt = s >> 1, kt = s & 1;
    int n  = rt * 16 + (lane & 15);
    int k0 = kt * 32 + (lane >> 4) * 8;
    short8 o;
    #pragma unroll
    for (int j = 0; j < 8; j++) o[j] = (short)f2bf(t[k0 + j][n]);
    long base = (((long)((nb >> 4) + rt) * ldk + (kb >> 5) + kt) << 9);
    *(short8*)&Bt[base + lane * 8] = o;
  }
}

// ---------------- V transpose ----------------
__global__ void vtrans_k(const short* __restrict__ vb, short* __restrict__ vtb, int stride){
  int s0 = blockIdx.x * 64, kv = blockIdx.y;
  int tid = threadIdx.x;
  int s = s0 + (tid & 63);
  int d0 = (tid >> 6) * 8;
  #pragma unroll
  for (int p = 0; p < 4; p++){
    int d = d0 + p * 32;
    short8 v = *(const short8*)&vb[(long)s * stride + kv * HDIM + d];
    #pragma unroll
    for (int j = 0; j < 8; j++)
      vtb[(long)(kv * HDIM + d + j) * TS + s] = v[j];
  }
}

// ---------------- RoPE apply (in-place bf16, row-major qkv buffer) ----------------
__global__ void rope_apply_k(short* __restrict__ buf, const float* __restrict__ cosT,
                             const float* __restrict__ sinT, int nh, int stride, int coloff){
  int idx = blockIdx.x * 256 + threadIdx.x;  // TS*nh*64
  int j = idx & 63;
  int t = idx >> 6;
  int hh = t % nh;
  int s = t / nh;
  long base = (long)s * stride + coloff + hh * HDIM + j;
  float c = cosT[s * 64 + j], sn = sinT[s * 64 + j];
  float x1 = bf2f(buf[base]), x2 = bf2f(buf[base + 64]);
  buf[base]      = (short)f2bf(x1 * c - x2 * sn);
  buf[base + 64] = (short)f2bf(x2 * c + x1 * sn);
}

// ================= 256x256 GEMM, BK=64, one barrier per tile (R16) =================
// Used for QKV/gate/up/Wo/down (short-K / split-K dispatches -- measured
// faster there). EPI: 1 bf16, 3 bf16 silu, 4 bf16 Xtra*acc (TILED, ldkC),
// 5 f32 partial@slice.
template<int EPI>
__global__ __launch_bounds__(512, 2)
void gemm256(const short* __restrict__ A, int ldkA,
             const short* __restrict__ Bt, int ldkB,
             float* __restrict__ Cf, short* __restrict__ Cb,
             const short* __restrict__ Xtra, int N, int K, int ldkC){
  __shared__ short lds[2][2][16384];   // [buf][A/B][32 subtiles x 512 shorts]
  const int tid = threadIdx.x;
  const int wid = tid >> 6, lane = tid & 63;
  const int wr = wid >> 2, wc = wid & 3;
  const int fr = lane & 15, fch = lane >> 4;
  const int nt2 = K >> 6;              // BK=64 tiles; nt2 even for all shapes

  const int z = blockIdx.y;
  const int k0 = z * (K >> 5);         // base in 32-k subtile units

  const int nbt = N >> 8;
  const int nwg = nbt << 3;            // 8 mb-tiles (M = 2048)
  const int q = nwg >> 3;
  const int swz = (blockIdx.x & 7) * q + (blockIdx.x >> 3);
  const int mb = swz & 7, nb = swz >> 3;

  const short* Abase = A  + ((long)(mb * 16) * ldkA + k0) * 512 + lane * 8;
  const short* Bbase = Bt + ((long)(nb * 16) * ldkB + k0) * 512 + lane * 8;
  const int gA0 = wid * 2, gA1 = wid * 2 + 1;   // this wave's stage rowtiles

  short8 aE[4], aO[4], bE[2], bO[2];
  f32x4 acc[8][4] = {};

#define STG64(bufc, tt) do{ \
    const int t2_ = (tt) * 2; \
    gload16(Abase + ((long)gA0 * ldkA + t2_    ) * 512, &lds[bufc][0][(gA0 * 2 + 0) * 512]); \
    gload16(Abase + ((long)gA0 * ldkA + t2_ + 1) * 512, &lds[bufc][0][(gA0 * 2 + 1) * 512]); \
    gload16(Abase + ((long)gA1 * ldkA + t2_    ) * 512, &lds[bufc][0][(gA1 * 2 + 0) * 512]); \
    gload16(Abase + ((long)gA1 * ldkA + t2_ + 1) * 512, &lds[bufc][0][(gA1 * 2 + 1) * 512]); \
    gload16(Bbase + ((long)gA0 * ldkB + t2_    ) * 512, &lds[bufc][1][(gA0 * 2 + 0) * 512]); \
    gload16(Bbase + ((long)gA0 * ldkB + t2_ + 1) * 512, &lds[bufc][1][(gA0 * 2 + 1) * 512]); \
    gload16(Bbase + ((long)gA1 * ldkB + t2_    ) * 512, &lds[bufc][1][(gA1 * 2 + 0) * 512]); \
    gload16(Bbase + ((long)gA1 * ldkB + t2_ + 1) * 512, &lds[bufc][1][(gA1 * 2 + 1) * 512]); \
  }while(0)
#define RDA64(dst, bufc, mh, kt) do{ \
    _Pragma("unroll") \
    for (int j_ = 0; j_ < 4; j_++) \
      dst[j_] = *(const short8*)&lds[bufc][0][(((wr * 8 + (mh) * 4 + j_) * 2) + (kt)) * 512 + fch * 128 + fr * 8]; \
  }while(0)
#define RDB64(dst, bufc, nh, kt) do{ \
    _Pragma("unroll") \
    for (int i_ = 0; i_ < 2; i_++) \
      dst[i_] = *(const short8*)&lds[bufc][1][(((wc * 4 + (nh) * 2 + i_) * 2) + (kt)) * 512 + fch * 128 + fr * 8]; \
  }while(0)
#define MM8(va, vb, mh, nh) do{ \
    __builtin_amdgcn_s_setprio(1); \
    _Pragma("unroll") \
    for (int j_ = 0; j_ < 4; j_++) \
      _Pragma("unroll") \
      for (int i_ = 0; i_ < 2; i_++) \
        acc[(mh)*4+j_][(nh)*2+i_] = mfma16(va[j_], vb[i_], acc[(mh)*4+j_][(nh)*2+i_]); \
    __builtin_amdgcn_s_setprio(0); \
  }while(0)

#define TILE64(t_, bufR, bufS) do{ \
    const int ts_ = ((t_) + 1 < nt2) ? (t_) + 1 : (t_); \
    STG64(bufS, ts_); \
    RDA64(aE, bufR, 0, 0); RDB64(bE, bufR, 0, 0); MM8(aE, bE, 0, 0); \
    RDB64(bO, bufR, 1, 0); MM8(aE, bO, 0, 1); \
    RDA64(aO, bufR, 1, 0); MM8(aO, bO, 1, 1); MM8(aO, bE, 1, 0); \
    RDA64(aE, bufR, 0, 1); RDB64(bE, bufR, 0, 1); MM8(aE, bE, 0, 0); \
    RDB64(bO, bufR, 1, 1); MM8(aE, bO, 0, 1); \
    RDA64(aO, bufR, 1, 1); MM8(aO, bO, 1, 1); MM8(aO, bE, 1, 0); \
    asm volatile("s_waitcnt vmcnt(0)" ::: "memory"); \
    __builtin_amdgcn_s_barrier(); \
  }while(0)

  STG64(0, 0);
  asm volatile("s_waitcnt vmcnt(0)" ::: "memory");
  __builtin_amdgcn_s_barrier();

  for (int it = 0; it < nt2; it += 2){
    TILE64(it,     0, 1);
    TILE64(it + 1, 1, 0);
  }

#undef STG64
#undef RDA64
#undef RDB64
#undef MM8
#undef TILE64

  const int rb0 = mb * 256 + wr * 128 + fch * 4;
  const int cb0 = nb * 256 + wc * 64 + fr;
  const long pbase = (EPI == 5) ? (long)z * ((long)TS * N) : 0;
  #pragma unroll
  for (int m = 0; m < 8; m++)
    #pragma unroll
    for (int n = 0; n < 4; n++)
      #pragma unroll
      for (int i = 0; i < 4; i++){
        const int rr = rb0 + m * 16 + i, cc = cb0 + n * 16;
        long idx = (long)rr * N + cc;
        float v = acc[m][n][i];
        if constexpr (EPI == 1) Cb[idx] = (short)f2bf(v);
        else if constexpr (EPI == 3){
          float sg = 1.0f / (1.0f + __expf(-v));
          Cb[idx] = (short)f2bf(v * sg);
        } else if constexpr (EPI == 4){
          float g = bf2f(Xtra[idx]);
          Cb[toff(rr, cc, ldkC)] = (short)f2bf(g * v);
        } else if constexpr (EPI == 5){
          Cf[pbase + idx] = v;
        } else {
          Cf[idx] = v;
        }
      }
}

// ================= 256x256 GEMM, depth-3 BK=32 (R14) -- lm_head =================
template<int EPI>
__global__ __launch_bounds__(512, 2)
void gemm256_d3(const short* __restrict__ A, int ldkA,
                const short* __restrict__ Bt, int ldkB,
                float* __restrict__ Cf, short* __restrict__ Cb,
                const short* __restrict__ Xtra, int N, int K, int ldkC){
  __shared__ short lds[4][2][8192];    // [buf][A/B][16 subtiles x 512]
  const int tid = threadIdx.x;
  const int wid = tid >> 6, lane = tid & 63;
  const int wr = wid >> 2, wc = wid & 3;
  const int fr = lane & 15, fch = lane >> 4;
  const int nt = K >> 5;               // BK=32 tiles; nt % 4 == 0

  const int z = blockIdx.y;
  const int k0 = z * nt;

  const int nbt = N >> 8;
  const int nwg = nbt << 3;            // 8 mb-tiles (M = 2048)
  const int q = nwg >> 3;
  const int swz = (blockIdx.x & 7) * q + (blockIdx.x >> 3);
  const int mb = swz & 7, nb = swz >> 3;

  const short* Abase = A  + ((long)(mb * 16) * ldkA + k0) * 512 + lane * 8;
  const short* Bbase = Bt + ((long)(nb * 16) * ldkB + k0) * 512 + lane * 8;
  const int gA0 = wid * 2, gA1 = wid * 2 + 1;

  short8 aE[4], aO[4], bE[2], bO[2];
  f32x4 acc[8][4] = {};

#define STG_A(bufc, g_, tau_) \
  gload16(Abase + ((long)(g_) * ldkA + (tau_)) * 512, &lds[bufc][0][(g_) * 512])
#define STG_B(bufc, g_, tau_) \
  gload16(Bbase + ((long)(g_) * ldkB + (tau_)) * 512, &lds[bufc][1][(g_) * 512])
#define RDA(dst, bufc, mh) do{ \
    _Pragma("unroll") \
    for (int j_ = 0; j_ < 4; j_++) \
      dst[j_] = *(const short8*)&lds[bufc][0][(wr * 8 + (mh) * 4 + j_) * 512 + fch * 128 + fr * 8]; \
  }while(0)
#define RDB(dst, bufc, nh) do{ \
    _Pragma("unroll") \
    for (int i_ = 0; i_ < 2; i_++) \
      dst[i_] = *(const short8*)&lds[bufc][1][(wc * 4 + (nh) * 2 + i_) * 512 + fch * 128 + fr * 8]; \
  }while(0)
#define MM8(va, vb, mh, nh) do{ \
    __builtin_amdgcn_s_setprio(1); \
    _Pragma("unroll") \
    for (int j_ = 0; j_ < 4; j_++) \
      _Pragma("unroll") \
      for (int i_ = 0; i_ < 2; i_++) \
        acc[(mh)*4+j_][(nh)*2+i_] = mfma16(va[j_], vb[i_], acc[(mh)*4+j_][(nh)*2+i_]); \
    __builtin_amdgcn_s_setprio(0); \
  }while(0)
#define SB __builtin_amdgcn_sched_barrier(0)

#define TILE(t_, bufR, bufN, bufS, bC, bNx) do{ \
    const int tau_ = ((t_) + 3 < nt) ? (t_) + 3 : nt - 1; \
    RDB(bNx, bufR, 1); STG_A(bufS, gA0, tau_); SB; MM8(aE, bC, 0, 0); \
    RDA(aO,  bufR, 1); STG_A(bufS, gA1, tau_); SB; MM8(aE, bNx, 0, 1); \
    asm volatile("s_waitcnt vmcnt(6)" ::: "memory"); \
    __builtin_amdgcn_s_barrier(); \
    RDA(aE,  bufN, 0); STG_B(bufS, gA0, tau_); SB; MM8(aO, bNx, 1, 1); \
    RDB(bNx, bufN, 0); STG_B(bufS, gA1, tau_); SB; MM8(aO, bC, 1, 0); \
    __builtin_amdgcn_s_barrier(); \
  }while(0)

  STG_A(0, gA0, 0); STG_A(0, gA1, 0); STG_B(0, gA0, 0); STG_B(0, gA1, 0);
  STG_A(1, gA0, 1); STG_A(1, gA1, 1); STG_B(1, gA0, 1); STG_B(1, gA1, 1);
  STG_A(2, gA0, 2); STG_A(2, gA1, 2); STG_B(2, gA0, 2); STG_B(2, gA1, 2);
  asm volatile("s_waitcnt vmcnt(8)" ::: "memory");
  __builtin_amdgcn_s_barrier();
  RDA(aE, 0, 0); RDB(bE, 0, 0);

  const int nIter = nt >> 2;
  for (int it = 0; it < nIter; ++it){
    const int t0 = it << 2;
    TILE(t0 + 0, 0, 1, 3, bE, bO);
    TILE(t0 + 1, 1, 2, 0, bO, bE);
    TILE(t0 + 2, 2, 3, 1, bE, bO);
    TILE(t0 + 3, 3, 0, 2, bO, bE);
  }
  asm volatile("s_waitcnt vmcnt(0)" ::: "memory");

#undef STG_A
#undef STG_B
#undef RDA
#undef RDB
#undef MM8
#undef SB
#undef TILE

  const int rb0 = mb * 256 + wr * 128 + fch * 4;
  const int cb0 = nb * 256 + wc * 64 + fr;
  const long pbase = (EPI == 5) ? (long)z * ((long)TS * N) : 0;
  #pragma unroll
  for (int m = 0; m < 8; m++)
    #pragma unroll
    for (int n = 0; n < 4; n++)
      #pragma unroll
      for (int i = 0; i < 4; i++){
        const int rr = rb0 + m * 16 + i, cc = cb0 + n * 16;
        long idx = (long)rr * N + cc;
        float v = acc[m][n][i];
        if constexpr (EPI == 1) Cb[idx] = (short)f2bf(v);
        else if constexpr (EPI == 3){
          float sg = 1.0f / (1.0f + __expf(-v));
          Cb[idx] = (short)f2bf(v * sg);
        } else if constexpr (EPI == 4){
          float g = bf2f(Xtra[idx]);
          Cb[toff(rr, cc, ldkC)] = (short)f2bf(g * v);
        } else if constexpr (EPI == 5){
          Cf[pbase + idx] = v;
        } else {
          Cf[idx] = v;
        }
      }
}

// ---------------- flash attention (LDS-free K/V: fragments read directly
// from L2-resident global; no barriers in the main loop) ----------------
__device__ __forceinline__ int qoff(int r, int cB){ return r * 256 + (cB ^ ((r & 7) << 4)); }
__device__ __forceinline__ int poff(int r, int cB){ return r * 128 + (cB ^ ((r & 7) << 4)); }

__global__ __launch_bounds__(256)
void attn_k(const short* __restrict__ qb, const short* __restrict__ kb,
            const short* __restrict__ vtb, short* __restrict__ ob){
  __shared__ short Qs[64 * 128];
  __shared__ short Ps[64 * 64];
  const int tid = threadIdx.x, wave = tid >> 6, lane = tid & 63;
  const int head = blockIdx.y, kvh = head >> 1;
  // causal load-balance: complementary qt across head bit 3 (R14, verified)
  const int qt = (head & 8) ? (31 - blockIdx.x) : blockIdx.x;
  const float scale = 0.08838834764831845f;  // 1/sqrt(128)

  {
    int r0 = tid >> 4, c16 = tid & 15;
    #pragma unroll
    for (int p = 0; p < 4; p++){
      int r = r0 + p * 16;
      u32x4 v = *(const u32x4*)&qb[(long)(qt * 64 + r) * QKVN + head * HDIM + c16 * 8];
      *(u32x4*)((char*)Qs + qoff(r, c16 * 16)) = v;
    }
  }
  __syncthreads();   // Q visible; the only barrier

  // per-lane fragment sub-addresses
  const int fr16 = lane & 15, fh8 = (lane >> 4) * 8;
  // K fragment (tile kt, k4, n): kb[(kt*64 + n*16 + fr16)*QKVN + kvh*128 + k4*32 + fh8]
  const short* kfb = kb + (long)kvh * HDIM + (long)fr16 * QKVN + fh8;
  // V fragment (tile kt, ks, n): vtb[(kvh*128 + n*16 + fr16)*TS + kt*64 + ks*32 + fh8]
  const short* vfb = vtb + ((long)(kvh * HDIM) + fr16) * TS + fh8;

  float mrun[4] = {-1e30f, -1e30f, -1e30f, -1e30f};
  float lrun[4] = {0.f, 0.f, 0.f, 0.f};
  f32x4 accO[8] = {};

  for (int kt = 0; kt <= qt; kt++){
    // QK^T: B-fragments straight from global (L2-resident K panel)
    f32x4 sacc[4] = {};
    const short* kf = kfb + (long)(kt * 64) * QKVN;
    #pragma unroll
    for (int k4 = 0; k4 < 4; k4++){
      short8 aq = *(const short8*)((const char*)Qs +
                   qoff(wave * 16 + fr16, k4 * 64 + (lane >> 4) * 16));
      #pragma unroll
      for (int n = 0; n < 4; n++){
        short8 bk = *(const short8*)&kf[(long)(n * 16) * QKVN + k4 * 32];
        sacc[n] = mfma16(aq, bk, sacc[n]);
      }
    }

    const bool diag = (kt == qt);
    float mt[4] = {-1e30f, -1e30f, -1e30f, -1e30f};
    #pragma unroll
    for (int n = 0; n < 4; n++)
      #pragma unroll
      for (int i = 0; i < 4; i++){
        float v = sacc[n][i] * scale;
        if (diag){
          int rr = (lane >> 4) * 4 + i + wave * 16;
          int cc = n * 16 + fr16;
          if (cc > rr) v = -1e30f;
        }
        sacc[n][i] = v;
        mt[i] = fmaxf(mt[i], v);
      }
    #pragma unroll
    for (int off = 1; off < 16; off <<= 1)
      #pragma unroll
      for (int i = 0; i < 4; i++) mt[i] = fmaxf(mt[i], __shfl_xor(mt[i], off));
    float alpha[4], rsum[4];
    #pragma unroll
    for (int i = 0; i < 4; i++){
      float mn = fmaxf(mrun[i], mt[i]);
      alpha[i] = __expf(mrun[i] - mn);
      mrun[i] = mn;
      rsum[i] = 0.f;
    }
    #pragma unroll
    for (int n = 0; n < 4; n++)
      #pragma unroll
      for (int i = 0; i < 4; i++){
        float p = __expf(sacc[n][i] - mrun[i]);
        sacc[n][i] = p;
        rsum[i] += p;
      }
    #pragma unroll
    for (int off = 1; off < 16; off <<= 1)
      #pragma unroll
      for (int i = 0; i < 4; i++) rsum[i] += __shfl_xor(rsum[i], off);
    #pragma unroll
    for (int i = 0; i < 4; i++) lrun[i] = lrun[i] * alpha[i] + rsum[i];

    // P -> LDS (wave-local rows; no cross-wave use -> no barrier)
    #pragma unroll
    for (int n = 0; n < 4; n++)
      #pragma unroll
      for (int i = 0; i < 4; i++){
        int rr = wave * 16 + (lane >> 4) * 4 + i;
        int cc = n * 16 + fr16;
        *(short*)((char*)Ps + poff(rr, cc * 2)) = (short)f2bf(sacc[n][i]);
      }

    #pragma unroll
    for (int n = 0; n < 8; n++)
      #pragma unroll
      for (int i = 0; i < 4; i++) accO[n][i] *= alpha[i];
    // PV: B-fragments straight from global (d-major V panel)
    const short* vf = vfb + kt * 64;
    #pragma unroll
    for (int ks = 0; ks < 2; ks++){
      short8 ap = *(const short8*)((const char*)Ps +
                   poff(wave * 16 + fr16, ks * 64 + (lane >> 4) * 16));
      #pragma unroll
      for (int n = 0; n < 8; n++){
        short8 bv = *(const short8*)&vf[(long)(n * 16) * TS + ks * 32];
        accO[n] = mfma16(ap, bv, accO[n]);
      }
    }
  }

  #pragma unroll
  for (int i = 0; i < 4; i++){
    float inv = 1.0f / lrun[i];
    int rr = qt * 64 + wave * 16 + (lane >> 4) * 4 + i;
    #pragma unroll
    for (int n = 0; n < 8; n++){
      int cc = head * HDIM + n * 16 + fr16;
      ob[toff(rr, cc, DM >> 5)] = (short)f2bf(accO[n][i] * inv);
    }
  }
}

// ---------------- host ----------------
extern "C" void kernel_launch(void* const* d_in, const int* in_sizes, int n_in,
                              void* d_out, int out_size, void* d_ws, size_t ws_size,
                              hipStream_t stream){
  (void)in_sizes; (void)n_in; (void)out_size; (void)ws_size;
  const int*   ids = (const int*)d_in[0];
  const float* E   = (const float*)d_in[1];
  const float* Wq  = (const float*)d_in[2];
  const float* Wk  = (const float*)d_in[3];
  const float* Wv  = (const float*)d_in[4];
  const float* Wo  = (const float*)d_in[5];
  const float* Wg  = (const float*)d_in[6];
  const float* Wu  = (const float*)d_in[7];
  const float* Wd  = (const float*)d_in[8];
  const float* nA  = (const float*)d_in[9];
  const float* nM  = (const float*)d_in[10];
  const float* nF  = (const float*)d_in[11];
  const float* LMH = (const float*)d_in[12];
  float* out = (float*)d_out;

  char* ws = (char*)d_ws;
  size_t off = 0;
  auto alloc = [&](size_t bytes){ void* p = ws + off; off += (bytes + 255) & ~(size_t)255; return p; };
  float* h    = (float*)alloc((size_t)TS * DM * 4);
  short* xb   = (short*)alloc((size_t)TS * DM * 2);       // tiled, ldk=64
  short* qkvb = (short*)alloc((size_t)TS * QKVN * 2);     // row-major [S][4096]
  short* vtb  = (short*)alloc((size_t)NKVH * HDIM * TS * 2);
  short* obuf = (short*)alloc((size_t)TS * DM * 2);       // tiled, ldk=64
  short* sg   = (short*)alloc((size_t)TS * FFD * 2);      // row-major
  short* actb = (short*)alloc((size_t)TS * FFD * 2);      // tiled, ldk=256
  float* cosT = (float*)alloc((size_t)TS * 64 * 4);
  float* sinT = (float*)alloc((size_t)TS * 64 * 4);
  short* wT   = (short*)alloc((size_t)NVOC * DM * 2);     // tiled weights; tail = partials
  float* pPart = (float*)((char*)wT + (size_t)36 * 1024 * 1024);

  rope_tables_k<<<512, 256, 0, stream>>>(cosT, sinT);
  embed_k<<<TS, 256, 0, stream>>>(ids, E, h);
  rmsnorm_k<<<TS, 256, 0, stream>>>(h, nA, xb);   // layer-0 attn pre-norm

  for (int l = 0; l < 2; l++){
    // fused QKV: wT rowtiles [0,128)=Wq^T, [128,192)=Wk^T, [192,256)=Wv^T (ldk=64)
    transpose_k<<<dim3(32, 32), 256, 0, stream>>>(Wq + (size_t)l * DM * DM, wT, DM, DM);
    transpose_k<<<dim3(16, 32), 256, 0, stream>>>(Wk + (size_t)l * DM * 1024, wT + (size_t)2048 * DM, DM, 1024);
    transpose_k<<<dim3(16, 32), 256, 0, stream>>>(Wv + (size_t)l * DM * 1024, wT + (size_t)3072 * DM, DM, 1024);
    gemm256<1><<<dim3(128), 512, 0, stream>>>(xb, 64, wT, 64, nullptr, qkvb, nullptr, QKVN, DM, 0);
    // RoPE on q and k slices (row-major qkvb); V transpose
    rope_apply_k<<<8192, 256, 0, stream>>>(qkvb, cosT, sinT, NHEAD, QKVN, 0);
    rope_apply_k<<<4096, 256, 0, stream>>>(qkvb, cosT, sinT, NKVH, QKVN, 2048);
    vtrans_k<<<dim3(32, 8), 256, 0, stream>>>(qkvb + 3072, vtb, QKVN);
    // attention (writes obuf tiled)
    attn_k<<<dim3(32, 16), 256, 0, stream>>>(qkvb, qkvb + 2048, vtb, obuf);
    // h += o @ Wo[l]  (split-K=4) ; fused reduce + MLP pre-norm
    transpose_k<<<dim3(32, 32), 256, 0, stream>>>(Wo + (size_t)l * DM * DM, wT, DM, DM);
    gemm256<5><<<dim3(64, 4), 512, 0, stream>>>(obuf, 64, wT, 64, pPart, nullptr, nullptr, DM, DM / 4, 0);
    reduce_rms_k<<<TS, 256, 0, stream>>>(pPart, h, nM + (size_t)l * DM, xb);
    // MLP
    transpose_k<<<dim3(128, 32), 256, 0, stream>>>(Wg + (size_t)l * DM * FFD, wT, DM, FFD);
    gemm256<3><<<dim3(256), 512, 0, stream>>>(xb, 64, wT, 64, nullptr, sg, nullptr, FFD, DM, 0);
    transpose_k<<<dim3(128, 32), 256, 0, stream>>>(Wu + (size_t)l * DM * FFD, wT, DM, FFD);
    gemm256<4><<<dim3(256), 512, 0, stream>>>(xb, 64, wT, 64, nullptr, actb, sg, FFD, DM, FFD >> 5);
    // down-proj: split-K=4; fused reduce + next pre-norm
    transpose_k<<<dim3(32, 128), 256, 0, stream>>>(Wd + (size_t)l * FFD * DM, wT, FFD, DM);
    gemm256<5><<<dim3(64, 4), 512, 0, stream>>>(actb, 256, wT, 256, pPart, nullptr, nullptr, DM, FFD / 4, 0);
    if (l == 0)
      reduce_rms_k<<<TS, 256, 0, stream>>>(pPart, h, nA + (size_t)DM, xb);
    else
      reduce_rms_k<<<TS, 256, 0, stream>>>(pPart, h, nF, xb);
  }

  transpose_k<<<dim3(500, 32), 256, 0, stream>>>(LMH, wT, DM, NVOC);
  gemm256_d3<0><<<dim3(1000), 512, 0, stream>>>(xb, 64, wT, 64, out, nullptr, nullptr, NVOC, DM, 0);
}

// Round 20
// 1283.585 us; speedup vs baseline: 1.1497x; 1.1497x over previous
//
#include <hip/hip_runtime.h>
#include <cstdint>
#include <cstddef>

typedef __attribute__((ext_vector_type(4))) float f32x4;
typedef __attribute__((ext_vector_type(8))) short short8;
typedef __attribute__((ext_vector_type(4))) unsigned int u32x4;

static const int TS = 2048;      // sequence length
static const int DM = 2048;      // d_model
static const int NHEAD = 16, NKVH = 8, HDIM = 128;
static const int FFD = 8192;
static const int NVOC = 32000;
static const int QKVN = 4096;    // fused QKV output width (2048 q + 1024 k + 1024 v)

__device__ __forceinline__ unsigned short f2bf(float f){
  unsigned int u = __builtin_bit_cast(unsigned int, f);
  u += 0x7FFFu + ((u >> 16) & 1u);
  return (unsigned short)(u >> 16);
}
__device__ __forceinline__ float bf2f(short h){
  unsigned int u = ((unsigned int)(unsigned short)h) << 16;
  return __builtin_bit_cast(float, u);
}
__device__ __forceinline__ f32x4 mfma16(short8 a, short8 b, f32x4 c){
  return __builtin_amdgcn_mfma_f32_16x16x32_bf16(a, b, c, 0, 0, 0);
}
__device__ __forceinline__ void gload16(const void* g, void* l){
  __builtin_amdgcn_global_load_lds(
      (const __attribute__((address_space(1))) unsigned int*)g,
      (__attribute__((address_space(3))) unsigned int*)l, 16, 0, 0);
}
// tiled operand layout: [rowtile r>>4][ktile k>>5] 512-elem fragment-major
// subtile; within: elem (r&15, k&31) at ((k&31)>>3)*128 + (r&15)*8 + (k&7).
__device__ __forceinline__ long toff(int r, int k, int ldk){
  return ((long)((r >> 4) * ldk + (k >> 5)) << 9)
       + (((k & 31) >> 3) << 7) + ((r & 15) << 3) + (k & 7);
}

// ---------------- RoPE tables ----------------
__global__ void rope_tables_k(float* __restrict__ cosT, float* __restrict__ sinT){
  int idx = blockIdx.x * 256 + threadIdx.x;   // TS*64 entries
  int s = idx >> 6, j = idx & 63;
  float inv = exp2f(-(float)j * (13.287712379549449f / 64.0f)); // 10000^(-j/64)
  float ang = (float)s * inv;
  cosT[idx] = cosf(ang);
  sinT[idx] = sinf(ang);
}

// ---------------- embedding gather ----------------
__global__ void embed_k(const int* __restrict__ ids, const float* __restrict__ E,
                        float* __restrict__ h){
  int s = blockIdx.x, tid = threadIdx.x;
  long id = ids[s];
  const f32x4* src = (const f32x4*)(E + id * (long)DM);
  f32x4* dst = (f32x4*)(h + (long)s * DM);
  dst[tid] = src[tid];
  dst[tid + 256] = src[tid + 256];
}

// ---------------- RMSNorm (f32 in -> bf16 out, TILED) ----------------
__global__ void rmsnorm_k(const float* __restrict__ x, const float* __restrict__ w,
                          short* __restrict__ out){
  int s = blockIdx.x, tid = threadIdx.x;
  const float* row = x + (long)s * DM;
  f32x4 v0 = *(const f32x4*)&row[tid * 8];
  f32x4 v1 = *(const f32x4*)&row[tid * 8 + 4];
  float ss = v0[0]*v0[0] + v0[1]*v0[1] + v0[2]*v0[2] + v0[3]*v0[3]
           + v1[0]*v1[0] + v1[1]*v1[1] + v1[2]*v1[2] + v1[3]*v1[3];
  #pragma unroll
  for (int off = 32; off; off >>= 1) ss += __shfl_xor(ss, off);
  __shared__ float sred[4];
  int wave = tid >> 6, lane = tid & 63;
  if (lane == 0) sred[wave] = ss;
  __syncthreads();
  float tot = sred[0] + sred[1] + sred[2] + sred[3];
  float r = rsqrtf(tot * (1.0f / (float)DM) + 1e-5f);
  f32x4 w0 = *(const f32x4*)&w[tid * 8];
  f32x4 w1 = *(const f32x4*)&w[tid * 8 + 4];
  short8 o;
  #pragma unroll
  for (int j = 0; j < 4; j++) o[j] = (short)f2bf(v0[j] * r * w0[j]);
  #pragma unroll
  for (int j = 0; j < 4; j++) o[4 + j] = (short)f2bf(v1[j] * r * w1[j]);
  *(short8*)&out[toff(s, tid * 8, DM >> 5)] = o;
}

// ---------------- fused split-K reduce + RMSNorm ----------------
__global__ void reduce_rms_k(const float* __restrict__ p, float* __restrict__ h,
                             const float* __restrict__ w, short* __restrict__ out){
  const long stride = (long)TS * DM;
  int s = blockIdx.x, tid = threadIdx.x;
  long i = (long)s * DM + tid * 8;
  f32x4 a0 = *(const f32x4*)&h[i];
  f32x4 a1 = *(const f32x4*)&h[i + 4];
  {
    f32x4 v0 = *(const f32x4*)&p[i];
    f32x4 v1 = *(const f32x4*)&p[i + stride];
    f32x4 v2 = *(const f32x4*)&p[i + 2 * stride];
    f32x4 v3 = *(const f32x4*)&p[i + 3 * stride];
    a0 = a0 + ((v0 + v1) + (v2 + v3));
  }
  {
    f32x4 v0 = *(const f32x4*)&p[i + 4];
    f32x4 v1 = *(const f32x4*)&p[i + 4 + stride];
    f32x4 v2 = *(const f32x4*)&p[i + 4 + 2 * stride];
    f32x4 v3 = *(const f32x4*)&p[i + 4 + 3 * stride];
    a1 = a1 + ((v0 + v1) + (v2 + v3));
  }
  *(f32x4*)&h[i] = a0;
  *(f32x4*)&h[i + 4] = a1;
  float ss = a0[0]*a0[0] + a0[1]*a0[1] + a0[2]*a0[2] + a0[3]*a0[3]
           + a1[0]*a1[0] + a1[1]*a1[1] + a1[2]*a1[2] + a1[3]*a1[3];
  #pragma unroll
  for (int off = 32; off; off >>= 1) ss += __shfl_xor(ss, off);
  __shared__ float sred[4];
  int wave = tid >> 6, lane = tid & 63;
  if (lane == 0) sred[wave] = ss;
  __syncthreads();
  float tot = sred[0] + sred[1] + sred[2] + sred[3];
  float r = rsqrtf(tot * (1.0f / (float)DM) + 1e-5f);
  f32x4 w0 = *(const f32x4*)&w[tid * 8];
  f32x4 w1 = *(const f32x4*)&w[tid * 8 + 4];
  short8 o;
  #pragma unroll
  for (int j = 0; j < 4; j++) o[j] = (short)f2bf(a0[j] * r * w0[j]);
  #pragma unroll
  for (int j = 0; j < 4; j++) o[4 + j] = (short)f2bf(a1[j] * r * w1[j]);
  *(short8*)&out[toff(s, tid * 8, DM >> 5)] = o;
}

// ---------------- weight transpose+convert: B[K][N] f32 -> tiled Bt (bf16) ----------------
__global__ void transpose_k(const float* __restrict__ B, short* __restrict__ Bt,
                            int K, int N){
  __shared__ float t[64][65];
  int tid = threadIdx.x;
  int kb = blockIdx.y * 64, nb = blockIdx.x * 64;
  int r0 = tid >> 4, c4 = tid & 15;
  const int ldk = K >> 5;
  #pragma unroll
  for (int p = 0; p < 4; p++){
    int r = r0 + p * 16;
    f32x4 v = *(const f32x4*)&B[(long)(kb + r) * N + nb + c4 * 4];
    t[r][c4*4+0] = v[0]; t[r][c4*4+1] = v[1]; t[r][c4*4+2] = v[2]; t[r][c4*4+3] = v[3];
  }
  __syncthreads();
  int wave = tid >> 6, lane = tid & 63;
  #pragma unroll
  for (int p = 0; p < 2; p++){
    int s = wave * 2 + p;
    int rt = s >> 1, kt = s & 1;
    int n  = rt * 16 + (lane & 15);
    int k0 = kt * 32 + (lane >> 4) * 8;
    short8 o;
    #pragma unroll
    for (int j = 0; j < 8; j++) o[j] = (short)f2bf(t[k0 + j][n]);
    long base = (((long)((nb >> 4) + rt) * ldk + (kb >> 5) + kt) << 9);
    *(short8*)&Bt[base + lane * 8] = o;
  }
}

// ---------------- V transpose ----------------
__global__ void vtrans_k(const short* __restrict__ vb, short* __restrict__ vtb, int stride){
  int s0 = blockIdx.x * 64, kv = blockIdx.y;
  int tid = threadIdx.x;
  int s = s0 + (tid & 63);
  int d0 = (tid >> 6) * 8;
  #pragma unroll
  for (int p = 0; p < 4; p++){
    int d = d0 + p * 32;
    short8 v = *(const short8*)&vb[(long)s * stride + kv * HDIM + d];
    #pragma unroll
    for (int j = 0; j < 8; j++)
      vtb[(long)(kv * HDIM + d + j) * TS + s] = v[j];
  }
}

// ---------------- RoPE apply (in-place bf16, row-major qkv buffer) ----------------
__global__ void rope_apply_k(short* __restrict__ buf, const float* __restrict__ cosT,
                             const float* __restrict__ sinT, int nh, int stride, int coloff){
  int idx = blockIdx.x * 256 + threadIdx.x;  // TS*nh*64
  int j = idx & 63;
  int t = idx >> 6;
  int hh = t % nh;
  int s = t / nh;
  long base = (long)s * stride + coloff + hh * HDIM + j;
  float c = cosT[s * 64 + j], sn = sinT[s * 64 + j];
  float x1 = bf2f(buf[base]), x2 = bf2f(buf[base + 64]);
  buf[base]      = (short)f2bf(x1 * c - x2 * sn);
  buf[base + 64] = (short)f2bf(x2 * c + x1 * sn);
}

// ================= 256x256 GEMM, BK=64, one barrier per tile (R16) =================
// Used for QKV/gate/up/Wo/down (short-K / split-K dispatches -- measured
// faster there). EPI: 1 bf16, 3 bf16 silu, 4 bf16 Xtra*acc (TILED, ldkC),
// 5 f32 partial@slice.
template<int EPI>
__global__ __launch_bounds__(512, 2)
void gemm256(const short* __restrict__ A, int ldkA,
             const short* __restrict__ Bt, int ldkB,
             float* __restrict__ Cf, short* __restrict__ Cb,
             const short* __restrict__ Xtra, int N, int K, int ldkC){
  __shared__ short lds[2][2][16384];   // [buf][A/B][32 subtiles x 512 shorts]
  const int tid = threadIdx.x;
  const int wid = tid >> 6, lane = tid & 63;
  const int wr = wid >> 2, wc = wid & 3;
  const int fr = lane & 15, fch = lane >> 4;
  const int nt2 = K >> 6;              // BK=64 tiles; nt2 even for all shapes

  const int z = blockIdx.y;
  const int k0 = z * (K >> 5);         // base in 32-k subtile units

  const int nbt = N >> 8;
  const int nwg = nbt << 3;            // 8 mb-tiles (M = 2048)
  const int q = nwg >> 3;
  const int swz = (blockIdx.x & 7) * q + (blockIdx.x >> 3);
  const int mb = swz & 7, nb = swz >> 3;

  const short* Abase = A  + ((long)(mb * 16) * ldkA + k0) * 512 + lane * 8;
  const short* Bbase = Bt + ((long)(nb * 16) * ldkB + k0) * 512 + lane * 8;
  const int gA0 = wid * 2, gA1 = wid * 2 + 1;   // this wave's stage rowtiles

  short8 aE[4], aO[4], bE[2], bO[2];
  f32x4 acc[8][4] = {};

#define STG64(bufc, tt) do{ \
    const int t2_ = (tt) * 2; \
    gload16(Abase + ((long)gA0 * ldkA + t2_    ) * 512, &lds[bufc][0][(gA0 * 2 + 0) * 512]); \
    gload16(Abase + ((long)gA0 * ldkA + t2_ + 1) * 512, &lds[bufc][0][(gA0 * 2 + 1) * 512]); \
    gload16(Abase + ((long)gA1 * ldkA + t2_    ) * 512, &lds[bufc][0][(gA1 * 2 + 0) * 512]); \
    gload16(Abase + ((long)gA1 * ldkA + t2_ + 1) * 512, &lds[bufc][0][(gA1 * 2 + 1) * 512]); \
    gload16(Bbase + ((long)gA0 * ldkB + t2_    ) * 512, &lds[bufc][1][(gA0 * 2 + 0) * 512]); \
    gload16(Bbase + ((long)gA0 * ldkB + t2_ + 1) * 512, &lds[bufc][1][(gA0 * 2 + 1) * 512]); \
    gload16(Bbase + ((long)gA1 * ldkB + t2_    ) * 512, &lds[bufc][1][(gA1 * 2 + 0) * 512]); \
    gload16(Bbase + ((long)gA1 * ldkB + t2_ + 1) * 512, &lds[bufc][1][(gA1 * 2 + 1) * 512]); \
  }while(0)
#define RDA64(dst, bufc, mh, kt) do{ \
    _Pragma("unroll") \
    for (int j_ = 0; j_ < 4; j_++) \
      dst[j_] = *(const short8*)&lds[bufc][0][(((wr * 8 + (mh) * 4 + j_) * 2) + (kt)) * 512 + fch * 128 + fr * 8]; \
  }while(0)
#define RDB64(dst, bufc, nh, kt) do{ \
    _Pragma("unroll") \
    for (int i_ = 0; i_ < 2; i_++) \
      dst[i_] = *(const short8*)&lds[bufc][1][(((wc * 4 + (nh) * 2 + i_) * 2) + (kt)) * 512 + fch * 128 + fr * 8]; \
  }while(0)
#define MM8(va, vb, mh, nh) do{ \
    __builtin_amdgcn_s_setprio(1); \
    _Pragma("unroll") \
    for (int j_ = 0; j_ < 4; j_++) \
      _Pragma("unroll") \
      for (int i_ = 0; i_ < 2; i_++) \
        acc[(mh)*4+j_][(nh)*2+i_] = mfma16(va[j_], vb[i_], acc[(mh)*4+j_][(nh)*2+i_]); \
    __builtin_amdgcn_s_setprio(0); \
  }while(0)

#define TILE64(t_, bufR, bufS) do{ \
    const int ts_ = ((t_) + 1 < nt2) ? (t_) + 1 : (t_); \
    STG64(bufS, ts_); \
    RDA64(aE, bufR, 0, 0); RDB64(bE, bufR, 0, 0); MM8(aE, bE, 0, 0); \
    RDB64(bO, bufR, 1, 0); MM8(aE, bO, 0, 1); \
    RDA64(aO, bufR, 1, 0); MM8(aO, bO, 1, 1); MM8(aO, bE, 1, 0); \
    RDA64(aE, bufR, 0, 1); RDB64(bE, bufR, 0, 1); MM8(aE, bE, 0, 0); \
    RDB64(bO, bufR, 1, 1); MM8(aE, bO, 0, 1); \
    RDA64(aO, bufR, 1, 1); MM8(aO, bO, 1, 1); MM8(aO, bE, 1, 0); \
    asm volatile("s_waitcnt vmcnt(0)" ::: "memory"); \
    __builtin_amdgcn_s_barrier(); \
  }while(0)

  STG64(0, 0);
  asm volatile("s_waitcnt vmcnt(0)" ::: "memory");
  __builtin_amdgcn_s_barrier();

  for (int it = 0; it < nt2; it += 2){
    TILE64(it,     0, 1);
    TILE64(it + 1, 1, 0);
  }

#undef STG64
#undef RDA64
#undef RDB64
#undef MM8
#undef TILE64

  const int rb0 = mb * 256 + wr * 128 + fch * 4;
  const int cb0 = nb * 256 + wc * 64 + fr;
  const long pbase = (EPI == 5) ? (long)z * ((long)TS * N) : 0;
  #pragma unroll
  for (int m = 0; m < 8; m++)
    #pragma unroll
    for (int n = 0; n < 4; n++)
      #pragma unroll
      for (int i = 0; i < 4; i++){
        const int rr = rb0 + m * 16 + i, cc = cb0 + n * 16;
        long idx = (long)rr * N + cc;
        float v = acc[m][n][i];
        if constexpr (EPI == 1) Cb[idx] = (short)f2bf(v);
        else if constexpr (EPI == 3){
          float sg = 1.0f / (1.0f + __expf(-v));
          Cb[idx] = (short)f2bf(v * sg);
        } else if constexpr (EPI == 4){
          float g = bf2f(Xtra[idx]);
          Cb[toff(rr, cc, ldkC)] = (short)f2bf(g * v);
        } else if constexpr (EPI == 5){
          Cf[pbase + idx] = v;
        } else {
          Cf[idx] = v;
        }
      }
}

// ================= 256x256 GEMM, depth-3 BK=32 (R14) -- lm_head =================
template<int EPI>
__global__ __launch_bounds__(512, 2)
void gemm256_d3(const short* __restrict__ A, int ldkA,
                const short* __restrict__ Bt, int ldkB,
                float* __restrict__ Cf, short* __restrict__ Cb,
                const short* __restrict__ Xtra, int N, int K, int ldkC){
  __shared__ short lds[4][2][8192];    // [buf][A/B][16 subtiles x 512]
  const int tid = threadIdx.x;
  const int wid = tid >> 6, lane = tid & 63;
  const int wr = wid >> 2, wc = wid & 3;
  const int fr = lane & 15, fch = lane >> 4;
  const int nt = K >> 5;               // BK=32 tiles; nt % 4 == 0

  const int z = blockIdx.y;
  const int k0 = z * nt;

  const int nbt = N >> 8;
  const int nwg = nbt << 3;            // 8 mb-tiles (M = 2048)
  const int q = nwg >> 3;
  const int swz = (blockIdx.x & 7) * q + (blockIdx.x >> 3);
  const int mb = swz & 7, nb = swz >> 3;

  const short* Abase = A  + ((long)(mb * 16) * ldkA + k0) * 512 + lane * 8;
  const short* Bbase = Bt + ((long)(nb * 16) * ldkB + k0) * 512 + lane * 8;
  const int gA0 = wid * 2, gA1 = wid * 2 + 1;

  short8 aE[4], aO[4], bE[2], bO[2];
  f32x4 acc[8][4] = {};

#define STG_A(bufc, g_, tau_) \
  gload16(Abase + ((long)(g_) * ldkA + (tau_)) * 512, &lds[bufc][0][(g_) * 512])
#define STG_B(bufc, g_, tau_) \
  gload16(Bbase + ((long)(g_) * ldkB + (tau_)) * 512, &lds[bufc][1][(g_) * 512])
#define RDA(dst, bufc, mh) do{ \
    _Pragma("unroll") \
    for (int j_ = 0; j_ < 4; j_++) \
      dst[j_] = *(const short8*)&lds[bufc][0][(wr * 8 + (mh) * 4 + j_) * 512 + fch * 128 + fr * 8]; \
  }while(0)
#define RDB(dst, bufc, nh) do{ \
    _Pragma("unroll") \
    for (int i_ = 0; i_ < 2; i_++) \
      dst[i_] = *(const short8*)&lds[bufc][1][(wc * 4 + (nh) * 2 + i_) * 512 + fch * 128 + fr * 8]; \
  }while(0)
#define MM8(va, vb, mh, nh) do{ \
    __builtin_amdgcn_s_setprio(1); \
    _Pragma("unroll") \
    for (int j_ = 0; j_ < 4; j_++) \
      _Pragma("unroll") \
      for (int i_ = 0; i_ < 2; i_++) \
        acc[(mh)*4+j_][(nh)*2+i_] = mfma16(va[j_], vb[i_], acc[(mh)*4+j_][(nh)*2+i_]); \
    __builtin_amdgcn_s_setprio(0); \
  }while(0)
#define SB __builtin_amdgcn_sched_barrier(0)

#define TILE(t_, bufR, bufN, bufS, bC, bNx) do{ \
    const int tau_ = ((t_) + 3 < nt) ? (t_) + 3 : nt - 1; \
    RDB(bNx, bufR, 1); STG_A(bufS, gA0, tau_); SB; MM8(aE, bC, 0, 0); \
    RDA(aO,  bufR, 1); STG_A(bufS, gA1, tau_); SB; MM8(aE, bNx, 0, 1); \
    asm volatile("s_waitcnt vmcnt(6)" ::: "memory"); \
    __builtin_amdgcn_s_barrier(); \
    RDA(aE,  bufN, 0); STG_B(bufS, gA0, tau_); SB; MM8(aO, bNx, 1, 1); \
    RDB(bNx, bufN, 0); STG_B(bufS, gA1, tau_); SB; MM8(aO, bC, 1, 0); \
    __builtin_amdgcn_s_barrier(); \
  }while(0)

  STG_A(0, gA0, 0); STG_A(0, gA1, 0); STG_B(0, gA0, 0); STG_B(0, gA1, 0);
  STG_A(1, gA0, 1); STG_A(1, gA1, 1); STG_B(1, gA0, 1); STG_B(1, gA1, 1);
  STG_A(2, gA0, 2); STG_A(2, gA1, 2); STG_B(2, gA0, 2); STG_B(2, gA1, 2);
  asm volatile("s_waitcnt vmcnt(8)" ::: "memory");
  __builtin_amdgcn_s_barrier();
  RDA(aE, 0, 0); RDB(bE, 0, 0);

  const int nIter = nt >> 2;
  for (int it = 0; it < nIter; ++it){
    const int t0 = it << 2;
    TILE(t0 + 0, 0, 1, 3, bE, bO);
    TILE(t0 + 1, 1, 2, 0, bO, bE);
    TILE(t0 + 2, 2, 3, 1, bE, bO);
    TILE(t0 + 3, 3, 0, 2, bO, bE);
  }
  asm volatile("s_waitcnt vmcnt(0)" ::: "memory");

#undef STG_A
#undef STG_B
#undef RDA
#undef RDB
#undef MM8
#undef SB
#undef TILE

  const int rb0 = mb * 256 + wr * 128 + fch * 4;
  const int cb0 = nb * 256 + wc * 64 + fr;
  const long pbase = (EPI == 5) ? (long)z * ((long)TS * N) : 0;
  #pragma unroll
  for (int m = 0; m < 8; m++)
    #pragma unroll
    for (int n = 0; n < 4; n++)
      #pragma unroll
      for (int i = 0; i < 4; i++){
        const int rr = rb0 + m * 16 + i, cc = cb0 + n * 16;
        long idx = (long)rr * N + cc;
        float v = acc[m][n][i];
        if constexpr (EPI == 1) Cb[idx] = (short)f2bf(v);
        else if constexpr (EPI == 3){
          float sg = 1.0f / (1.0f + __expf(-v));
          Cb[idx] = (short)f2bf(v * sg);
        } else if constexpr (EPI == 4){
          float g = bf2f(Xtra[idx]);
          Cb[toff(rr, cc, ldkC)] = (short)f2bf(g * v);
        } else if constexpr (EPI == 5){
          Cf[pbase + idx] = v;
        } else {
          Cf[idx] = v;
        }
      }
}

// ---------------- flash attention (T14 async-STAGE: prefetch kt+1 K/V into
// registers before the LDS-write of kt; vmcnt wait lands after compute) -----
__device__ __forceinline__ int qoff(int r, int cB){ return r * 256 + (cB ^ ((r & 7) << 4)); }
__device__ __forceinline__ int voff(int d, int cB){ return d * 128 + (cB ^ ((d & 7) << 4)); }
__device__ __forceinline__ int poff(int r, int cB){ return r * 128 + (cB ^ ((r & 7) << 4)); }

__global__ __launch_bounds__(256)
void attn_k(const short* __restrict__ qb, const short* __restrict__ kb,
            const short* __restrict__ vtb, short* __restrict__ ob){
  __shared__ short Qs[64 * 128];
  __shared__ short Ks[64 * 128];
  __shared__ short Vt[128 * 64];
  __shared__ short Ps[64 * 64];
  const int tid = threadIdx.x, wave = tid >> 6, lane = tid & 63;
  const int head = blockIdx.y, kvh = head >> 1;
  // causal load-balance: complementary qt across head bit 3 (R14, verified)
  const int qt = (head & 8) ? (31 - blockIdx.x) : blockIdx.x;
  const float scale = 0.08838834764831845f;  // 1/sqrt(128)

  const int kr0 = tid >> 4, kc16 = tid & 15;
  const int vr0 = tid >> 3, vc = tid & 7;

  {
    #pragma unroll
    for (int p = 0; p < 4; p++){
      int r = kr0 + p * 16;
      u32x4 v = *(const u32x4*)&qb[(long)(qt * 64 + r) * QKVN + head * HDIM + kc16 * 8];
      *(u32x4*)((char*)Qs + qoff(r, kc16 * 16)) = v;
    }
  }

  // prologue: load tile 0's K/V into registers
  u32x4 kreg[4], vreg[4];
  #pragma unroll
  for (int p = 0; p < 4; p++)
    kreg[p] = *(const u32x4*)&kb[(long)(0 * 64 + kr0 + p * 16) * QKVN + kvh * HDIM + kc16 * 8];
  #pragma unroll
  for (int p = 0; p < 4; p++)
    vreg[p] = *(const u32x4*)&vtb[(long)(kvh * HDIM + vr0 + p * 32) * TS + 0 * 64 + vc * 8];

  float mrun[4] = {-1e30f, -1e30f, -1e30f, -1e30f};
  float lrun[4] = {0.f, 0.f, 0.f, 0.f};
  f32x4 accO[8] = {};

  for (int kt = 0; kt <= qt; kt++){
    __syncthreads();           // previous compute done reading Ks/Vt
    // issue next tile's loads FIRST (in flight across writes + compute)
    u32x4 kN[4], vN[4];
    if (kt < qt){
      #pragma unroll
      for (int p = 0; p < 4; p++)
        kN[p] = *(const u32x4*)&kb[(long)((kt + 1) * 64 + kr0 + p * 16) * QKVN + kvh * HDIM + kc16 * 8];
      #pragma unroll
      for (int p = 0; p < 4; p++)
        vN[p] = *(const u32x4*)&vtb[(long)(kvh * HDIM + vr0 + p * 32) * TS + (kt + 1) * 64 + vc * 8];
    }
    // write current tile from registers to LDS
    #pragma unroll
    for (int p = 0; p < 4; p++)
      *(u32x4*)((char*)Ks + qoff(kr0 + p * 16, kc16 * 16)) = kreg[p];
    #pragma unroll
    for (int p = 0; p < 4; p++)
      *(u32x4*)((char*)Vt + voff(vr0 + p * 32, vc * 16)) = vreg[p];
    __syncthreads();

    f32x4 sacc[4] = {};
    #pragma unroll
    for (int k4 = 0; k4 < 4; k4++){
      short8 aq = *(const short8*)((const char*)Qs +
                   qoff(wave * 16 + (lane & 15), k4 * 64 + (lane >> 4) * 16));
      #pragma unroll
      for (int n = 0; n < 4; n++){
        short8 bk = *(const short8*)((const char*)Ks +
                     qoff(n * 16 + (lane & 15), k4 * 64 + (lane >> 4) * 16));
        sacc[n] = mfma16(aq, bk, sacc[n]);
      }
    }

    const bool diag = (kt == qt);
    float mt[4] = {-1e30f, -1e30f, -1e30f, -1e30f};
    #pragma unroll
    for (int n = 0; n < 4; n++)
      #pragma unroll
      for (int i = 0; i < 4; i++){
        float v = sacc[n][i] * scale;
        if (diag){
          int rr = (lane >> 4) * 4 + i + wave * 16;
          int cc = n * 16 + (lane & 15);
          if (cc > rr) v = -1e30f;
        }
        sacc[n][i] = v;
        mt[i] = fmaxf(mt[i], v);
      }
    #pragma unroll
    for (int off = 1; off < 16; off <<= 1)
      #pragma unroll
      for (int i = 0; i < 4; i++) mt[i] = fmaxf(mt[i], __shfl_xor(mt[i], off));
    float alpha[4], rsum[4];
    #pragma unroll
    for (int i = 0; i < 4; i++){
      float mn = fmaxf(mrun[i], mt[i]);
      alpha[i] = __expf(mrun[i] - mn);
      mrun[i] = mn;
      rsum[i] = 0.f;
    }
    #pragma unroll
    for (int n = 0; n < 4; n++)
      #pragma unroll
      for (int i = 0; i < 4; i++){
        float p = __expf(sacc[n][i] - mrun[i]);
        sacc[n][i] = p;
        rsum[i] += p;
      }
    #pragma unroll
    for (int off = 1; off < 16; off <<= 1)
      #pragma unroll
      for (int i = 0; i < 4; i++) rsum[i] += __shfl_xor(rsum[i], off);
    #pragma unroll
    for (int i = 0; i < 4; i++) lrun[i] = lrun[i] * alpha[i] + rsum[i];

    #pragma unroll
    for (int n = 0; n < 4; n++)
      #pragma unroll
      for (int i = 0; i < 4; i++){
        int rr = wave * 16 + (lane >> 4) * 4 + i;
        int cc = n * 16 + (lane & 15);
        *(short*)((char*)Ps + poff(rr, cc * 2)) = (short)f2bf(sacc[n][i]);
      }

    #pragma unroll
    for (int n = 0; n < 8; n++)
      #pragma unroll
      for (int i = 0; i < 4; i++) accO[n][i] *= alpha[i];
    #pragma unroll
    for (int ks = 0; ks < 2; ks++){
      short8 ap = *(const short8*)((const char*)Ps +
                   poff(wave * 16 + (lane & 15), ks * 64 + (lane >> 4) * 16));
      #pragma unroll
      for (int n = 0; n < 8; n++){
        short8 bv = *(const short8*)((const char*)Vt +
                     voff(n * 16 + (lane & 15), ks * 64 + (lane >> 4) * 16));
        accO[n] = mfma16(ap, bv, accO[n]);
      }
    }

    // rotate prefetched registers (compile-time indices; vmcnt wait lands here,
    // after the full compute phase -> latency hidden)
    if (kt < qt){
      #pragma unroll
      for (int p = 0; p < 4; p++){ kreg[p] = kN[p]; vreg[p] = vN[p]; }
    }
  }

  #pragma unroll
  for (int i = 0; i < 4; i++){
    float inv = 1.0f / lrun[i];
    int rr = qt * 64 + wave * 16 + (lane >> 4) * 4 + i;
    #pragma unroll
    for (int n = 0; n < 8; n++){
      int cc = head * HDIM + n * 16 + (lane & 15);
      ob[toff(rr, cc, DM >> 5)] = (short)f2bf(accO[n][i] * inv);
    }
  }
}

// ---------------- host ----------------
extern "C" void kernel_launch(void* const* d_in, const int* in_sizes, int n_in,
                              void* d_out, int out_size, void* d_ws, size_t ws_size,
                              hipStream_t stream){
  (void)in_sizes; (void)n_in; (void)out_size; (void)ws_size;
  const int*   ids = (const int*)d_in[0];
  const float* E   = (const float*)d_in[1];
  const float* Wq  = (const float*)d_in[2];
  const float* Wk  = (const float*)d_in[3];
  const float* Wv  = (const float*)d_in[4];
  const float* Wo  = (const float*)d_in[5];
  const float* Wg  = (const float*)d_in[6];
  const float* Wu  = (const float*)d_in[7];
  const float* Wd  = (const float*)d_in[8];
  const float* nA  = (const float*)d_in[9];
  const float* nM  = (const float*)d_in[10];
  const float* nF  = (const float*)d_in[11];
  const float* LMH = (const float*)d_in[12];
  float* out = (float*)d_out;

  char* ws = (char*)d_ws;
  size_t off = 0;
  auto alloc = [&](size_t bytes){ void* p = ws + off; off += (bytes + 255) & ~(size_t)255; return p; };
  float* h    = (float*)alloc((size_t)TS * DM * 4);
  short* xb   = (short*)alloc((size_t)TS * DM * 2);       // tiled, ldk=64
  short* qkvb = (short*)alloc((size_t)TS * QKVN * 2);     // row-major [S][4096]
  short* vtb  = (short*)alloc((size_t)NKVH * HDIM * TS * 2);
  short* obuf = (short*)alloc((size_t)TS * DM * 2);       // tiled, ldk=64
  short* sg   = (short*)alloc((size_t)TS * FFD * 2);      // row-major
  short* actb = (short*)alloc((size_t)TS * FFD * 2);      // tiled, ldk=256
  float* cosT = (float*)alloc((size_t)TS * 64 * 4);
  float* sinT = (float*)alloc((size_t)TS * 64 * 4);
  short* wT   = (short*)alloc((size_t)NVOC * DM * 2);     // tiled weights; tail = partials
  float* pPart = (float*)((char*)wT + (size_t)36 * 1024 * 1024);

  rope_tables_k<<<512, 256, 0, stream>>>(cosT, sinT);
  embed_k<<<TS, 256, 0, stream>>>(ids, E, h);
  rmsnorm_k<<<TS, 256, 0, stream>>>(h, nA, xb);   // layer-0 attn pre-norm

  for (int l = 0; l < 2; l++){
    // fused QKV: wT rowtiles [0,128)=Wq^T, [128,192)=Wk^T, [192,256)=Wv^T (ldk=64)
    transpose_k<<<dim3(32, 32), 256, 0, stream>>>(Wq + (size_t)l * DM * DM, wT, DM, DM);
    transpose_k<<<dim3(16, 32), 256, 0, stream>>>(Wk + (size_t)l * DM * 1024, wT + (size_t)2048 * DM, DM, 1024);
    transpose_k<<<dim3(16, 32), 256, 0, stream>>>(Wv + (size_t)l * DM * 1024, wT + (size_t)3072 * DM, DM, 1024);
    gemm256<1><<<dim3(128), 512, 0, stream>>>(xb, 64, wT, 64, nullptr, qkvb, nullptr, QKVN, DM, 0);
    // RoPE on q and k slices (row-major qkvb); V transpose
    rope_apply_k<<<8192, 256, 0, stream>>>(qkvb, cosT, sinT, NHEAD, QKVN, 0);
    rope_apply_k<<<4096, 256, 0, stream>>>(qkvb, cosT, sinT, NKVH, QKVN, 2048);
    vtrans_k<<<dim3(32, 8), 256, 0, stream>>>(qkvb + 3072, vtb, QKVN);
    // attention (writes obuf tiled)
    attn_k<<<dim3(32, 16), 256, 0, stream>>>(qkvb, qkvb + 2048, vtb, obuf);
    // h += o @ Wo[l]  (split-K=4) ; fused reduce + MLP pre-norm
    transpose_k<<<dim3(32, 32), 256, 0, stream>>>(Wo + (size_t)l * DM * DM, wT, DM, DM);
    gemm256<5><<<dim3(64, 4), 512, 0, stream>>>(obuf, 64, wT, 64, pPart, nullptr, nullptr, DM, DM / 4, 0);
    reduce_rms_k<<<TS, 256, 0, stream>>>(pPart, h, nM + (size_t)l * DM, xb);
    // MLP
    transpose_k<<<dim3(128, 32), 256, 0, stream>>>(Wg + (size_t)l * DM * FFD, wT, DM, FFD);
    gemm256<3><<<dim3(256), 512, 0, stream>>>(xb, 64, wT, 64, nullptr, sg, nullptr, FFD, DM, 0);
    transpose_k<<<dim3(128, 32), 256, 0, stream>>>(Wu + (size_t)l * DM * FFD, wT, DM, FFD);
    gemm256<4><<<dim3(256), 512, 0, stream>>>(xb, 64, wT, 64, nullptr, actb, sg, FFD, DM, FFD >> 5);
    // down-proj: split-K=4; fused reduce + next pre-norm
    transpose_k<<<dim3(32, 128), 256, 0, stream>>>(Wd + (size_t)l * FFD * DM, wT, FFD, DM);
    gemm256<5><<<dim3(64, 4), 512, 0, stream>>>(actb, 256, wT, 256, pPart, nullptr, nullptr, DM, FFD / 4, 0);
    if (l == 0)
      reduce_rms_k<<<TS, 256, 0, stream>>>(pPart, h, nA + (size_t)DM, xb);
    else
      reduce_rms_k<<<TS, 256, 0, stream>>>(pPart, h, nF, xb);
  }

  transpose_k<<<dim3(500, 32), 256, 0, stream>>>(LMH, wT, DM, NVOC);
  gemm256_d3<0><<<dim3(1000), 512, 0, stream>>>(xb, 64, wT, 64, out, nullptr, nullptr, NVOC, DM, 0);
}